// Round 6
// baseline (290.154 us; speedup 1.0000x reference)
//
#include <hip/hip_runtime.h>
#include <hip/hip_bf16.h>

#define B_   4
#define N_   16384
#define T_   65536
static constexpr float SCALE_F = 0.17677669529663687f; // 32^-0.5

typedef __attribute__((ext_vector_type(8))) short bf16x8;
typedef __attribute__((ext_vector_type(4))) float f32x4;

static __device__ __forceinline__ unsigned pk2bf(float lo, float hi) {
    __hip_bfloat162 t = __float22bfloat162_rn(make_float2(lo, hi));
    union { __hip_bfloat162 h; unsigned u; } c; c.h = t; return c.u;
}
static __device__ __forceinline__ unsigned short f2bf(float f) {
    unsigned u = __float_as_uint(f);
    u += 0x7fffu + ((u >> 16) & 1u);
    return (unsigned short)(u >> 16);
}

// ---------------- prep: Wt_bf (3 blocks) + S1t/cvec (257 blocks) ------------
__global__ __launch_bounds__(256) void prep_all(
    const float* __restrict__ Wq, const float* __restrict__ Wk,
    const float* __restrict__ Wv, unsigned short* __restrict__ Wt,
    const float* __restrict__ Wr, const float* __restrict__ br,
    const float* __restrict__ Wout, const float* __restrict__ bout,
    float* __restrict__ S1t, float* __restrict__ cvec)
{
    const int blk = blockIdx.x;
    if (blk < 3) {
        const float* W = (blk == 0) ? Wq : (blk == 1) ? Wk : Wv;
        unsigned short* dst = Wt + (size_t)blk * 65536 + (size_t)threadIdx.x * 256;
        #pragma unroll 4
        for (int kb = 0; kb < 32; ++kb) {
            float v[8];
            #pragma unroll
            for (int e = 0; e < 8; ++e) v[e] = W[(kb*8 + e)*256 + threadIdx.x];
            uint4 w;
            w.x = pk2bf(v[0], v[1]); w.y = pk2bf(v[2], v[3]);
            w.z = pk2bf(v[4], v[5]); w.w = pk2bf(v[6], v[7]);
            *reinterpret_cast<uint4*>(dst + kb*8) = w;
        }
        return;
    }
    const int i = blk - 3, j = threadIdx.x;
    if (i < 256) {
        const int h = i >> 5, dd = i & 31;
        float s = 0.f;
        #pragma unroll 8
        for (int dp = 0; dp < 32; ++dp)
            s = fmaf(Wr[dd*32 + dp], Wout[(h*32 + dp)*256 + j], s);
        S1t[(size_t)j*256 + i] = s;
    } else {
        float cj = bout[j];
        for (int r = 0; r < 256; ++r) cj = fmaf(br[r & 31], Wout[r*256 + j], cj);
        cvec[j] = cj;
    }
}

// ---------------- K1: QKV projection — zero-LDS direct-reg MFMA stream ------
// grid (1024, 3), 256 thr / 4 waves. Tile 64 M x 256 N, K=256 fully unrolled.
// A: global->reg f32 (32B/lane contiguous), cvt in reg. B: L2-resident Wt.
// No LDS, no barriers: one flat DAG, compiler schedules loads.
__global__ __launch_bounds__(256) void proj_mfma(
    const float* __restrict__ states, const float* __restrict__ agent_qs,
    const float* __restrict__ obs, const unsigned short* __restrict__ Wt,
    const float* __restrict__ bq, const float* __restrict__ bk,
    const float* __restrict__ bv,
    unsigned short* __restrict__ q_bf, unsigned short* __restrict__ k_bf,
    unsigned short* __restrict__ v_bf)
{
    const int tid = threadIdx.x;
    const int z  = blockIdx.y;
    const int t0 = blockIdx.x * 64;

    const float* X = (z == 0) ? states : (z == 1) ? agent_qs : obs;
    const unsigned short* Bt = Wt + (size_t)z * 65536;
    const float* bias = (z == 0) ? bq : (z == 1) ? bk : bv;
    unsigned short* Y = (z == 0) ? q_bf : (z == 1) ? k_bf : v_bf;
    const bool doabs = (z == 0);

    const int wid = tid >> 6, lane = tid & 63;
    const int l15 = lane & 15, g = lane >> 4;
    const int wc = wid;

    // column permutation: frag coord n' -> true col c = [n'5][n'3:2][n'4][n'1:0]
    // (gives 64B-dense epilogue stores; A/B share the natural k-bijection)
    const float* abase[4];
    const unsigned short* bbase[4];
    #pragma unroll
    for (int mi = 0; mi < 4; ++mi)
        abase[mi] = X + (size_t)(t0 + mi*16 + l15) * 256 + g*8;
    #pragma unroll
    for (int ni = 0; ni < 4; ++ni) {
        int np = ni*16 + l15;
        int c = (np & 32) | ((np & 12) << 1) | ((np & 16) >> 2) | (np & 3);
        bbase[ni] = Bt + (size_t)(wc*64 + c) * 256 + g*8;
    }

    f32x4 acc[4][4];
    #pragma unroll
    for (int mi = 0; mi < 4; ++mi)
        #pragma unroll
        for (int ni = 0; ni < 4; ++ni) acc[mi][ni] = (f32x4){0.f,0.f,0.f,0.f};

    #pragma unroll
    for (int kk = 0; kk < 8; ++kk) {
        bf16x8 bb[4], a[4];
        #pragma unroll
        for (int ni = 0; ni < 4; ++ni)
            bb[ni] = *reinterpret_cast<const bf16x8*>(bbase[ni] + kk*32);
        #pragma unroll
        for (int mi = 0; mi < 4; ++mi) {
            f32x4 lo = *reinterpret_cast<const f32x4*>(abase[mi] + kk*32);
            f32x4 hi = *reinterpret_cast<const f32x4*>(abase[mi] + kk*32 + 4);
            union { unsigned u[4]; bf16x8 v; } cc;
            cc.u[0] = pk2bf(lo[0], lo[1]);
            cc.u[1] = pk2bf(lo[2], lo[3]);
            cc.u[2] = pk2bf(hi[0], hi[1]);
            cc.u[3] = pk2bf(hi[2], hi[3]);
            a[mi] = cc.v;
        }
        #pragma unroll
        for (int mi = 0; mi < 4; ++mi)
            #pragma unroll
            for (int ni = 0; ni < 4; ++ni)
                acc[mi][ni] = __builtin_amdgcn_mfma_f32_16x16x32_bf16(
                    bb[ni], a[mi], acc[mi][ni], 0, 0, 0);
    }

    // epilogue: store s covers true cols wc*64 + s*32 + g*8 + [0,8)
    #pragma unroll
    for (int s = 0; s < 2; ++s) {
        int colb = wc*64 + s*32 + g*8;
        float4 b0 = *reinterpret_cast<const float4*>(bias + colb);
        float4 b1 = *reinterpret_cast<const float4*>(bias + colb + 4);
        #pragma unroll
        for (int mi = 0; mi < 4; ++mi) {
            int m = t0 + mi*16 + l15;
            float y0 = acc[mi][2*s  ][0] + b0.x;
            float y1 = acc[mi][2*s  ][1] + b0.y;
            float y2 = acc[mi][2*s  ][2] + b0.z;
            float y3 = acc[mi][2*s  ][3] + b0.w;
            float y4 = acc[mi][2*s+1][0] + b1.x;
            float y5 = acc[mi][2*s+1][1] + b1.y;
            float y6 = acc[mi][2*s+1][2] + b1.z;
            float y7 = acc[mi][2*s+1][3] + b1.w;
            if (doabs) {
                y0 = fabsf(y0); y1 = fabsf(y1); y2 = fabsf(y2); y3 = fabsf(y3);
                y4 = fabsf(y4); y5 = fabsf(y5); y6 = fabsf(y6); y7 = fabsf(y7);
            }
            uint4 pk;
            pk.x = pk2bf(y0, y1); pk.y = pk2bf(y2, y3);
            pk.z = pk2bf(y4, y5); pk.w = pk2bf(y6, y7);
            *reinterpret_cast<uint4*>(Y + (size_t)m*256 + colb) = pk;
        }
    }
}

// ---------------- pools: partial softmax pooling ----------------------------
// mode 0: coef = wqa*SCALE. mode 1: compute gq from part_in, coef = gq*wka*SCALE.
__global__ __launch_bounds__(512) void pool_partial(
    const unsigned short* __restrict__ data,
    const float* __restrict__ wqa, const float* __restrict__ wka,
    const float* __restrict__ part_in, float* __restrict__ part_out, int mode)
{
    const int bh = blockIdx.x, ch = blockIdx.y;
    const int b = bh >> 3, h = bh & 7;
    const int tid = threadIdx.x;

    __shared__ float coef[32];
    __shared__ float s_red[8];
    __shared__ float a_red[8][32];

    if (tid < 32) {
        float cc;
        if (mode == 0) cc = wqa[tid];
        else {
            float num = 0.f, den = 0.f;
            #pragma unroll
            for (int c = 0; c < 8; ++c) {
                num += part_in[(size_t)(bh*8 + c)*40 + tid];
                den += part_in[(size_t)(bh*8 + c)*40 + 32];
            }
            cc = (num / den) * wka[tid];
        }
        coef[tid] = cc * SCALE_F;
    }
    __syncthreads();
    float cf[32];
    #pragma unroll
    for (int d = 0; d < 32; ++d) cf[d] = coef[d];

    float s = 0.f;
    float acc[32];
    #pragma unroll
    for (int d = 0; d < 32; ++d) acc[d] = 0.f;

    const unsigned short* base = data + (size_t)b * N_ * 256 + h * 32;
    for (int n = ch*2048 + tid; n < (ch + 1)*2048; n += 512) {
        const uint4* p = reinterpret_cast<const uint4*>(base + (size_t)n * 256);
        float qv[32];
        #pragma unroll
        for (int gg = 0; gg < 4; ++gg) {
            uint4 r = p[gg];
            unsigned w0 = r.x, w1 = r.y, w2 = r.z, w3 = r.w;
            qv[gg*8+0] = __uint_as_float(w0 << 16);
            qv[gg*8+1] = __uint_as_float(w0 & 0xffff0000u);
            qv[gg*8+2] = __uint_as_float(w1 << 16);
            qv[gg*8+3] = __uint_as_float(w1 & 0xffff0000u);
            qv[gg*8+4] = __uint_as_float(w2 << 16);
            qv[gg*8+5] = __uint_as_float(w2 & 0xffff0000u);
            qv[gg*8+6] = __uint_as_float(w3 << 16);
            qv[gg*8+7] = __uint_as_float(w3 & 0xffff0000u);
        }
        float l = 0.f;
        #pragma unroll
        for (int d = 0; d < 32; ++d) l = fmaf(qv[d], cf[d], l);
        float e = expf(l);
        s += e;
        #pragma unroll
        for (int d = 0; d < 32; ++d) acc[d] = fmaf(e, qv[d], acc[d]);
    }

    #pragma unroll
    for (int off = 1; off < 64; off <<= 1) {
        s += __shfl_xor(s, off);
        #pragma unroll
        for (int d = 0; d < 32; ++d) acc[d] += __shfl_xor(acc[d], off);
    }
    const int wave = tid >> 6, lane = tid & 63;
    if (lane == 0) {
        s_red[wave] = s;
        #pragma unroll
        for (int d = 0; d < 32; ++d) a_red[wave][d] = acc[d];
    }
    __syncthreads();
    if (tid < 32) {
        float num = 0.f, den = 0.f;
        #pragma unroll
        for (int w2 = 0; w2 < 8; ++w2) { num += a_red[w2][tid]; den += s_red[w2]; }
        part_out[(size_t)(bh*8 + ch)*40 + tid] = num;
        if (tid == 0) part_out[(size_t)(bh*8 + ch)*40 + 32] = den;
    }
}

// ---------------- Wcat_t[b][n][k] bf16 (gk computed inline from part_k) -----
__global__ __launch_bounds__(256) void build_wcat_t(
    const float* __restrict__ part_k, const float* __restrict__ S1t,
    const float* __restrict__ Wout, unsigned short* __restrict__ Wcat_t)
{
    const int b = blockIdx.x, n = blockIdx.y, k = threadIdx.x;
    const int h = k >> 5, d = k & 31;
    float num = 0.f, den = 0.f;
    #pragma unroll
    for (int c = 0; c < 8; ++c) {
        num += part_k[(size_t)((b*8 + h)*8 + c)*40 + d];
        den += part_k[(size_t)((b*8 + h)*8 + c)*40 + 32];
    }
    const float gkv = num / den;
    unsigned short* dst = Wcat_t + (size_t)(b*256 + n) * 512;
    dst[k]       = f2bf(gkv * S1t[(size_t)n*256 + k]);
    dst[k + 256] = f2bf(Wout[(size_t)k*256 + n]);
}

// ---------------- K4: out = [v|q] @ Wcat_t[b]^T + cvec — zero-LDS stream ----
// grid (1024), 256 thr / 4 waves. Tile 64 M x 256 N, K=512 (8 v-steps + 8 q).
__global__ __launch_bounds__(256) void out_mfma(
    const unsigned short* __restrict__ v_bf, const unsigned short* __restrict__ q_bf,
    const unsigned short* __restrict__ Wcat_t, const float* __restrict__ cvec,
    float* __restrict__ out)
{
    const int tid = threadIdx.x;
    const int t0 = blockIdx.x * 64;
    const int b  = t0 >> 14;
    const unsigned short* Wb = Wcat_t + (size_t)b * 256 * 512;

    const int wid = tid >> 6, lane = tid & 63;
    const int l15 = lane & 15, g = lane >> 4, wc = wid;

    const unsigned short* av[4];
    const unsigned short* aq[4];
    const unsigned short* bbase[4];
    #pragma unroll
    for (int mi = 0; mi < 4; ++mi) {
        size_t row = (size_t)(t0 + mi*16 + l15) * 256 + g*8;
        av[mi] = v_bf + row;
        aq[mi] = q_bf + row;
    }
    #pragma unroll
    for (int ni = 0; ni < 4; ++ni)
        bbase[ni] = Wb + (size_t)(wc*64 + ni*16 + l15) * 512 + g*8;

    f32x4 acc[4][4];
    #pragma unroll
    for (int mi = 0; mi < 4; ++mi)
        #pragma unroll
        for (int ni = 0; ni < 4; ++ni) acc[mi][ni] = (f32x4){0.f,0.f,0.f,0.f};

    #pragma unroll
    for (int kk = 0; kk < 8; ++kk) {
        bf16x8 a[4], bb[4];
        #pragma unroll
        for (int ni = 0; ni < 4; ++ni)
            bb[ni] = *reinterpret_cast<const bf16x8*>(bbase[ni] + kk*32);
        #pragma unroll
        for (int mi = 0; mi < 4; ++mi)
            a[mi] = *reinterpret_cast<const bf16x8*>(av[mi] + kk*32);
        #pragma unroll
        for (int mi = 0; mi < 4; ++mi)
            #pragma unroll
            for (int ni = 0; ni < 4; ++ni)
                acc[mi][ni] = __builtin_amdgcn_mfma_f32_16x16x32_bf16(
                    bb[ni], a[mi], acc[mi][ni], 0, 0, 0);
    }
    #pragma unroll
    for (int kk = 8; kk < 16; ++kk) {
        bf16x8 a[4], bb[4];
        #pragma unroll
        for (int ni = 0; ni < 4; ++ni)
            bb[ni] = *reinterpret_cast<const bf16x8*>(bbase[ni] + kk*32);
        #pragma unroll
        for (int mi = 0; mi < 4; ++mi)
            a[mi] = *reinterpret_cast<const bf16x8*>(aq[mi] + (kk-8)*32);
        #pragma unroll
        for (int mi = 0; mi < 4; ++mi)
            #pragma unroll
            for (int ni = 0; ni < 4; ++ni)
                acc[mi][ni] = __builtin_amdgcn_mfma_f32_16x16x32_bf16(
                    bb[ni], a[mi], acc[mi][ni], 0, 0, 0);
    }

    #pragma unroll
    for (int ni = 0; ni < 4; ++ni) {
        int colb = wc*64 + ni*16 + g*4;
        float4 cv = *reinterpret_cast<const float4*>(cvec + colb);
        #pragma unroll
        for (int mi = 0; mi < 4; ++mi) {
            int m = t0 + mi*16 + l15;
            float4 o;
            o.x = acc[mi][ni][0] + cv.x;
            o.y = acc[mi][ni][1] + cv.y;
            o.z = acc[mi][ni][2] + cv.z;
            o.w = acc[mi][ni][3] + cv.w;
            *reinterpret_cast<float4*>(out + (size_t)m*256 + colb) = o;
        }
    }
}

extern "C" void kernel_launch(void* const* d_in, const int* in_sizes, int n_in,
                              void* d_out, int out_size, void* d_ws, size_t ws_size,
                              hipStream_t stream)
{
    const float* states   = (const float*)d_in[0];
    const float* agent_qs = (const float*)d_in[1];
    const float* obs      = (const float*)d_in[2];
    const float* Wq   = (const float*)d_in[3];
    const float* bq   = (const float*)d_in[4];
    const float* Wk   = (const float*)d_in[5];
    const float* bk   = (const float*)d_in[6];
    const float* Wv   = (const float*)d_in[7];
    const float* bv   = (const float*)d_in[8];
    const float* wq_attn = (const float*)d_in[9];
    const float* wk_attn = (const float*)d_in[10];
    const float* Wr   = (const float*)d_in[11];
    const float* br   = (const float*)d_in[12];
    const float* Wout = (const float*)d_in[13];
    const float* bout = (const float*)d_in[14];
    float* out = (float*)d_out;

    char* w = (char*)d_ws;
    unsigned short* q_bf = (unsigned short*)w; w += (size_t)T_ * 256 * 2;
    unsigned short* k_bf = (unsigned short*)w; w += (size_t)T_ * 256 * 2;
    unsigned short* v_bf = (unsigned short*)w; w += (size_t)T_ * 256 * 2;
    unsigned short* Wt_bf   = (unsigned short*)w; w += (size_t)3 * 65536 * 2;
    unsigned short* Wcat_t  = (unsigned short*)w; w += (size_t)4 * 256 * 512 * 2;
    float* part_q = (float*)w; w += (size_t)256 * 40 * sizeof(float);
    float* part_k = (float*)w; w += (size_t)256 * 40 * sizeof(float);
    float* S1t  = (float*)w; w += (size_t)256 * 256 * sizeof(float);
    float* cvec = (float*)w; w += 256 * sizeof(float);

    prep_all<<<dim3(260), 256, 0, stream>>>(Wq, Wk, Wv, Wt_bf,
                                            Wr, br, Wout, bout, S1t, cvec);
    proj_mfma<<<dim3(1024, 3), 256, 0, stream>>>(
        states, agent_qs, obs, Wt_bf, bq, bk, bv, q_bf, k_bf, v_bf);
    pool_partial<<<dim3(32, 8), 512, 0, stream>>>(q_bf, wq_attn, wk_attn,
                                                  part_q, part_q, 0);
    pool_partial<<<dim3(32, 8), 512, 0, stream>>>(k_bf, wq_attn, wk_attn,
                                                  part_q, part_k, 1);
    build_wcat_t<<<dim3(4, 256), 256, 0, stream>>>(part_k, S1t, Wout, Wcat_t);
    out_mfma<<<dim3(1024), 256, 0, stream>>>(v_bf, q_bf, Wcat_t, cvec, out);
}